// Round 12
// baseline (179.869 us; speedup 1.0000x reference)
//
#include <hip/hip_runtime.h>
#include <math.h>

typedef unsigned short ushort_t;
typedef __attribute__((ext_vector_type(8))) short bf16x8;
typedef __attribute__((ext_vector_type(4))) float f32x4;
typedef __attribute__((ext_vector_type(8))) unsigned short u16x8;
typedef __attribute__((ext_vector_type(2))) unsigned int u32x2;
typedef __attribute__((ext_vector_type(4))) unsigned int u32x4;

#define N_TOK 65536
#define DIN 128
#define HD 256
#define DOUT 128
#define NEXP 8
#define MT 64
#define MAX_TILES (N_TOK / MT) /* 1024 */

__device__ __forceinline__ unsigned short f2bf(float f) {
    union { float f; unsigned int i; } v; v.f = f;
    unsigned int i = v.i;
    return (unsigned short)((i + 0x7FFFu + ((i >> 16) & 1u)) >> 16); // RNE
}

#define RT_BLOCK 1024
#define RT_TPB 256    /* tokens per block: 2 passes x 128 */
#define RT_PASS 128

// ---------------------------------------------------------------------------
// Router + weight-pack (R11 verbatim -- passed at 178.5us).
// list_w top-1 entries stored NEGATED (sign = carrier flag: expert stores
// w*y+bo to out for top-1, w*y to y2 for top-2).
// ---------------------------------------------------------------------------
__global__ __launch_bounds__(RT_BLOCK)
void router_kernel(const float* __restrict__ x,
                   const float* __restrict__ Wg,
                   const float* __restrict__ W1,
                   const float* __restrict__ W2,
                   const float* __restrict__ Wo,
                   int* __restrict__ counts,
                   int* __restrict__ list_tok,
                   float* __restrict__ list_w,
                   ushort_t* __restrict__ wt1f,
                   ushort_t* __restrict__ wt2f,
                   ushort_t* __restrict__ wotf) {
    __shared__ float xs[RT_PASS * 132];   // 67.6KB, padded rows
    __shared__ float wgsT[NEXP * 132];    // transposed Wg, padded
    __shared__ int lcnt[NEXP];
    __shared__ int lbase[NEXP];
    int tid = threadIdx.x;
    if (tid < NEXP) lcnt[tid] = 0;
    if (tid < DIN * NEXP) {
        int ee = tid & 7, k = tid >> 3;   // Wg[k][e]
        wgsT[ee * 132 + k] = Wg[tid];
    }
    // pack_weights: 256 blocks x 400 chunks = 102400
    if (tid < 400) {
        int id = blockIdx.x * 400 + tid;
        const float* src; ushort_t* dst; int Nn, ksteps, c;
        if (id < 32768) {            // W1
            int ee = id >> 12; c = id & 4095;
            Nn = HD; ksteps = 4; src = W1 + (size_t)ee * DIN * HD; dst = wt1f + (size_t)id * 8;
        } else if (id < 98304) {     // W2
            int t = id - 32768; int ee = t >> 13; c = t & 8191;
            Nn = HD; ksteps = 8; src = W2 + (size_t)ee * HD * HD; dst = wt2f + (size_t)t * 8;
        } else {                     // Wo
            int t = id - 98304; c = t;
            Nn = DOUT; ksteps = 8; src = Wo; dst = wotf + (size_t)t * 8;
        }
        int L = c & 63; int kc = c >> 6;
        int kstep = kc % ksteps; int ntile = kc / ksteps;
        int qq = L >> 4, mm = L & 15;
        int n = ntile * 16 + mm; int k0 = kstep * 32 + qq * 8;
        u16x8 v;
#pragma unroll
        for (int j = 0; j < 8; j++) v[j] = f2bf(src[(size_t)(k0 + j) * Nn + n]);
        *(u16x8*)dst = v;
    }

    int e = tid & 7;
    int tl = tid >> 3;          // local token row, 0..127
    int re0[2], re1[2], rp0[2], rp1[2];
    float rw0[2], rw1[2];

#pragma unroll
    for (int p = 0; p < 2; p++) {
        __syncthreads();  // p0: wgsT/lcnt ready; p1: all lanes done reading xs
        // stage 128 token rows coalescedly
        {
            int row = tid >> 3;
            int f4 = tid & 7;
            const float4* src = (const float4*)(x + (size_t)(blockIdx.x * RT_TPB + p * RT_PASS + row) * DIN);
            float4* drow = (float4*)(xs + row * 132);
#pragma unroll
            for (int j = 0; j < 4; j++)
                drow[f4 + 8 * j] = src[f4 + 8 * j];
        }
        __syncthreads();

        const float4* xr = (const float4*)(xs + tl * 132);
        const float4* wv4 = (const float4*)(wgsT + e * 132);
        float lg = 0.f;
#pragma unroll 8
        for (int kk = 0; kk < 32; kk++) {
            float4 xv = xr[kk];
            float4 wv = wv4[kk];
            lg += xv.x * wv.x;
            lg += xv.y * wv.y;
            lg += xv.z * wv.z;
            lg += xv.w * wv.w;
        }
        // top-1 over the 8 lanes of this token (ties -> lowest expert index)
        float v0 = lg; int e0 = e;
#pragma unroll
        for (int d = 1; d < 8; d <<= 1) {
            float ov = __shfl_xor(v0, d, 64);
            int oe = __shfl_xor(e0, d, 64);
            if (ov > v0 || (ov == v0 && oe < e0)) { v0 = ov; e0 = oe; }
        }
        // top-2: mask out e0, reduce again
        float mv = (e == e0) ? -3.0e38f : lg;
        float v1 = mv; int e1 = e;
#pragma unroll
        for (int d = 1; d < 8; d <<= 1) {
            float ov = __shfl_xor(v1, d, 64);
            int oe = __shfl_xor(e1, d, 64);
            if (ov > v1 || (ov == v1 && oe < e1)) { v1 = ov; e1 = oe; }
        }
        float t = expf(v1 - v0);
        float inv = 1.0f / (1.0f + t);
        re0[p] = e0; re1[p] = e1;
        rw0[p] = inv; rw1[p] = t * inv;
        if (e == 0) {       // writer lane: local ranks unique across passes
            rp0[p] = atomicAdd(&lcnt[e0], 1);
            rp1[p] = atomicAdd(&lcnt[e1], 1);
        }
    }
    __syncthreads();
    if (tid < NEXP) lbase[tid] = atomicAdd(&counts[tid * 32], lcnt[tid]);
    __syncthreads();
    if (e == 0) {
#pragma unroll
        for (int p = 0; p < 2; p++) {
            int n = blockIdx.x * RT_TPB + p * RT_PASS + tl;
            int q0 = lbase[re0[p]] + rp0[p];
            list_tok[re0[p] * N_TOK + q0] = n;
            list_w[re0[p] * N_TOK + q0] = -rw0[p];   // negative = top-1 (out, +bo)
            int q1 = lbase[re1[p]] + rp1[p];
            list_tok[re1[p] * N_TOK + q1] = n;
            list_w[re1[p] * N_TOK + q1] = rw1[p];    // positive = top-2 (y2)
        }
    }
}

// ---------------------------------------------------------------------------
// Fused per-expert MLP, SWAPPED-GEMM form (R6 phase structure).
// ROUND-12 CHANGE: occupancy 3 -> 4 blocks/CU.
//   Diagnosis: latency-bound (MfmaUtil 19.5 / VALU 20.6 / Occ 26.5, all low);
//   MFMA pipe busy ~13.3us == its floor, so instruction-count reduction is
//   a non-lever; the lever is TLP. At (256,3) the kernel used 80 VGPR + 64
//   AGPR = 144 > 128, blocking the 4th block. The +32-reg cost was the
//   weight-fragment DOUBLE-BUFFERS, whose only job was single-block latency
//   hiding -- with 4 blocks/CU, TLP does that job. So: single-buffered
//   fragments (load at top of each kstep; compiler pipelines within budget)
//   + __launch_bounds__(256,4). Peak live set est. ~111 regs < 128.
//   NOT the R2 spill config: no grid-stride back-edge, no 3-slot ring.
//   SPILL WATCH: WRITE_SIZE must stay 65.5MB; any jump = spill = revert.
// + T5 s_setprio(1) around MFMA clusters (independent blocks at different
//   phases on a CU = the regime where setprio paid +4-7% on attn; ~free).
// NO ATOMICS: top-1 entries plain-store w*y+bo into out; top-2 entries
// store w*y into y2; trailing combine kernel does out += y2.
// ---------------------------------------------------------------------------
__global__ __launch_bounds__(256, 4)
void expert_kernel(const float* __restrict__ x,
                   const int* __restrict__ counts,
                   const int* __restrict__ list_tok,
                   const float* __restrict__ list_w,
                   const ushort_t* __restrict__ wt1f,
                   const ushort_t* __restrict__ wt2f,
                   const ushort_t* __restrict__ wotf,
                   const float* __restrict__ b1,
                   const float* __restrict__ b2,
                   const float* __restrict__ bo,
                   float* __restrict__ y2,
                   float* __restrict__ out) {
    int e = blockIdx.x & 7;
    int tile = blockIdx.x >> 3;
    int cnt = counts[e * 32];
    int base = tile * MT;
    if (base >= cnt) return;
    int rows = cnt - base; if (rows > MT) rows = MT;

    __shared__ __align__(16) ushort_t bufA[8192];  // 16KB: x chunks
    __shared__ __align__(16) ushort_t bufH[16384]; // 32KB: h1, then h2
    __shared__ int toks_s[MT];
    __shared__ float wts_s[MT];

    int tid = threadIdx.x;
    int lane = tid & 63;
    int w = tid >> 6;
    int q = lane >> 4;
    int mcol = lane & 15;

    const bf16x8* W1A = (const bf16x8*)(wt1f + (size_t)e * 4096 * 8);
    const bf16x8* W2A = (const bf16x8*)(wt2f + (size_t)e * 8192 * 8);
    const bf16x8* WoB = (const bf16x8*)wotf;
    const bf16x8* Albs = (const bf16x8*)bufA;
    const bf16x8* Hlbs = (const bf16x8*)bufH;

    if (tid < MT) {
        int rr = tid < rows ? tid : rows - 1;
        toks_s[tid] = list_tok[(size_t)e * N_TOK + base + rr];
        wts_s[tid] = list_w[(size_t)e * N_TOK + base + rr];
    }

    // stage x tile (fp32 -> bf16) into bufA, kchunk-fast (coalesced 512B/row)
    for (int c = tid; c < 1024; c += 256) {
        int row = c >> 4;
        int kchunk = c & 15;
        int rr = row < rows ? row : rows - 1;
        int tok = list_tok[(size_t)e * N_TOK + base + rr];
        const float4* src = (const float4*)(x + (size_t)tok * DIN + kchunk * 8);
        float4 lo = src[0], hi = src[1];
        unsigned p0, p1, p2, p3;
        asm("v_cvt_pk_bf16_f32 %0, %1, %2" : "=v"(p0) : "v"(lo.x), "v"(lo.y));
        asm("v_cvt_pk_bf16_f32 %0, %1, %2" : "=v"(p1) : "v"(lo.z), "v"(lo.w));
        asm("v_cvt_pk_bf16_f32 %0, %1, %2" : "=v"(p2) : "v"(hi.x), "v"(hi.y));
        asm("v_cvt_pk_bf16_f32 %0, %1, %2" : "=v"(p3) : "v"(hi.z), "v"(hi.w));
        int dchunk = ((kchunk >> 2) * 4 + (row >> 4)) * 64 + (kchunk & 3) * 16 + (row & 15);
        u32x4 v; v.x = p0; v.y = p1; v.z = p2; v.w = p3;
        *(u32x4*)(&bufA[dchunk * 8]) = v;
    }
    __syncthreads();

    // ---- GEMM1 (swapped): h1^T[n=256][t=64], wave w owns n rows w*64..+63
    f32x4 acc[4][4];
#pragma unroll
    for (int rtl = 0; rtl < 4; rtl++)
#pragma unroll
        for (int ct = 0; ct < 4; ct++) acc[rtl][ct] = (f32x4){0.f, 0.f, 0.f, 0.f};
#pragma unroll
    for (int ks = 0; ks < 4; ks++) {
        bf16x8 ar[4];
#pragma unroll
        for (int rtl = 0; rtl < 4; rtl++)
            ar[rtl] = W1A[((w * 4 + rtl) * 4 + ks) * 64 + lane];
        bf16x8 bf_[4];
#pragma unroll
        for (int ct = 0; ct < 4; ct++) bf_[ct] = Albs[(ks * 4 + ct) * 64 + lane];
        __builtin_amdgcn_s_setprio(1);
#pragma unroll
        for (int rtl = 0; rtl < 4; rtl++)
#pragma unroll
            for (int ct = 0; ct < 4; ct++)
                acc[rtl][ct] = __builtin_amdgcn_mfma_f32_16x16x32_bf16(ar[rtl], bf_[ct], acc[rtl][ct], 0, 0, 0);
        __builtin_amdgcn_s_setprio(0);
    }

    // JIT bias load (short live range)
    float4 b1v[4];
#pragma unroll
    for (int rtl = 0; rtl < 4; rtl++)
        b1v[rtl] = *(const float4*)(b1 + e * HD + w * 64 + rtl * 16 + q * 4);

    // epilogue 1: bias + relu -> h1 chunks in bufH (disjoint from bufA)
#pragma unroll
    for (int rtl = 0; rtl < 4; rtl++) {
        int ks2 = w * 2 + (rtl >> 1);
        int q2 = (rtl * 2 + (q >> 1)) & 3;
        int uoff = (ks2 * 4 * 64 + q2 * 16 + mcol) * 8 + (q & 1) * 4;
#pragma unroll
        for (int ct = 0; ct < 4; ct++) {
            float v0 = acc[rtl][ct][0] + b1v[rtl].x; v0 = v0 > 0.f ? v0 : 0.f;
            float v1 = acc[rtl][ct][1] + b1v[rtl].y; v1 = v1 > 0.f ? v1 : 0.f;
            float v2 = acc[rtl][ct][2] + b1v[rtl].z; v2 = v2 > 0.f ? v2 : 0.f;
            float v3 = acc[rtl][ct][3] + b1v[rtl].w; v3 = v3 > 0.f ? v3 : 0.f;
            unsigned d0, d1;
            asm("v_cvt_pk_bf16_f32 %0, %1, %2" : "=v"(d0) : "v"(v0), "v"(v1));
            asm("v_cvt_pk_bf16_f32 %0, %1, %2" : "=v"(d1) : "v"(v2), "v"(v3));
            u32x2 dd; dd.x = d0; dd.y = d1;
            *(u32x2*)(&bufH[uoff + ct * 512]) = dd;
        }
    }
    __syncthreads(); // h1 complete before GEMM2 reads

    // ---- GEMM2 (swapped): h2^T = W2^T @ h1^T, K=256 ----
    f32x4 acc2[4][4];
#pragma unroll
    for (int rtl = 0; rtl < 4; rtl++)
#pragma unroll
        for (int ct = 0; ct < 4; ct++) acc2[rtl][ct] = (f32x4){0.f, 0.f, 0.f, 0.f};
#pragma unroll
    for (int ks = 0; ks < 8; ks++) {
        bf16x8 ar[4];
#pragma unroll
        for (int rtl = 0; rtl < 4; rtl++)
            ar[rtl] = W2A[((w * 4 + rtl) * 8 + ks) * 64 + lane];
        bf16x8 bf_[4];
#pragma unroll
        for (int ct = 0; ct < 4; ct++) bf_[ct] = Hlbs[(ks * 4 + ct) * 64 + lane];
        __builtin_amdgcn_s_setprio(1);
#pragma unroll
        for (int rtl = 0; rtl < 4; rtl++)
#pragma unroll
            for (int ct = 0; ct < 4; ct++)
                acc2[rtl][ct] = __builtin_amdgcn_mfma_f32_16x16x32_bf16(ar[rtl], bf_[ct], acc2[rtl][ct], 0, 0, 0);
        __builtin_amdgcn_s_setprio(0);
    }

    // JIT bias load
    float4 b2v[4];
#pragma unroll
    for (int rtl = 0; rtl < 4; rtl++)
        b2v[rtl] = *(const float4*)(b2 + e * HD + w * 64 + rtl * 16 + q * 4);

    __syncthreads(); // all waves done reading h1 before h2 overwrite

    // epilogue 2: bias + relu -> h2 chunks
#pragma unroll
    for (int rtl = 0; rtl < 4; rtl++) {
        int ks2 = w * 2 + (rtl >> 1);
        int q2 = (rtl * 2 + (q >> 1)) & 3;
        int uoff = (ks2 * 4 * 64 + q2 * 16 + mcol) * 8 + (q & 1) * 4;
#pragma unroll
        for (int ct = 0; ct < 4; ct++) {
            float v0 = acc2[rtl][ct][0] + b2v[rtl].x; v0 = v0 > 0.f ? v0 : 0.f;
            float v1 = acc2[rtl][ct][1] + b2v[rtl].y; v1 = v1 > 0.f ? v1 : 0.f;
            float v2 = acc2[rtl][ct][2] + b2v[rtl].z; v2 = v2 > 0.f ? v2 : 0.f;
            float v3 = acc2[rtl][ct][3] + b2v[rtl].w; v3 = v3 > 0.f ? v3 : 0.f;
            unsigned d0, d1;
            asm("v_cvt_pk_bf16_f32 %0, %1, %2" : "=v"(d0) : "v"(v0), "v"(v1));
            asm("v_cvt_pk_bf16_f32 %0, %1, %2" : "=v"(d1) : "v"(v2), "v"(v3));
            u32x2 dd; dd.x = d0; dd.y = d1;
            *(u32x2*)(&bufH[uoff + ct * 512]) = dd;
        }
    }
    __syncthreads();

    // ---- GEMM3 (unswapped): y = h2 @ Wo; plain-store combine (no atomics) --
    f32x4 acc3[4][2];
#pragma unroll
    for (int mt = 0; mt < 4; mt++)
#pragma unroll
        for (int nt = 0; nt < 2; nt++) acc3[mt][nt] = (f32x4){0.f, 0.f, 0.f, 0.f};
#pragma unroll
    for (int ks = 0; ks < 8; ks++) {
        bf16x8 br[2];
#pragma unroll
        for (int nt = 0; nt < 2; nt++)
            br[nt] = WoB[((w * 2 + nt) * 8 + ks) * 64 + lane];
        bf16x8 af_[4];
#pragma unroll
        for (int mt = 0; mt < 4; mt++) af_[mt] = Hlbs[(ks * 4 + mt) * 64 + lane];
        __builtin_amdgcn_s_setprio(1);
#pragma unroll
        for (int nt = 0; nt < 2; nt++)
#pragma unroll
            for (int mt = 0; mt < 4; mt++)
                acc3[mt][nt] = __builtin_amdgcn_mfma_f32_16x16x32_bf16(af_[mt], br[nt], acc3[mt][nt], 0, 0, 0);
        __builtin_amdgcn_s_setprio(0);
    }
#pragma unroll
    for (int mt = 0; mt < 4; mt++) {
#pragma unroll
        for (int r = 0; r < 4; r++) {
            int row = mt * 16 + q * 4 + r;
            if (row < rows) {
                int tok = toks_s[row];
                float wraw = wts_s[row];
                float wgt = fabsf(wraw);
                bool carrier = wraw < 0.f;   // top-1: store to out, add bo once
                float* dst = (carrier ? out : y2) + (size_t)tok * DOUT;
#pragma unroll
                for (int nt = 0; nt < 2; nt++) {
                    int col = (w * 2 + nt) * 16 + mcol;
                    dst[col] = wgt * acc3[mt][nt][r] + (carrier ? bo[col] : 0.f);
                }
            }
        }
    }
}

// ---------------------------------------------------------------------------
// out += y2 (streaming, 96MB total traffic). Every token has exactly one
// top-1 store (already in out) and one top-2 store (in y2).
// ---------------------------------------------------------------------------
__global__ __launch_bounds__(256)
void combine_kernel(const float* __restrict__ y2, float* __restrict__ out) {
    int gid = blockIdx.x * 256 + threadIdx.x;
#pragma unroll
    for (int i = 0; i < 4; i++) {
        int idx = gid + i * (2048 * 256);
        float4 a = ((float4*)out)[idx];
        float4 b = ((const float4*)y2)[idx];
        a.x += b.x; a.y += b.y; a.z += b.z; a.w += b.w;
        ((float4*)out)[idx] = a;
    }
}

extern "C" void kernel_launch(void* const* d_in, const int* in_sizes, int n_in,
                              void* d_out, int out_size, void* d_ws, size_t ws_size,
                              hipStream_t stream) {
    const float* x  = (const float*)d_in[0];
    const float* Wg = (const float*)d_in[1];
    const float* W1 = (const float*)d_in[2];
    const float* b1 = (const float*)d_in[3];
    const float* W2 = (const float*)d_in[4];
    const float* b2 = (const float*)d_in[5];
    const float* Wo = (const float*)d_in[6];
    const float* bo = (const float*)d_in[7];
    float* out = (float*)d_out;

    char* ws = (char*)d_ws;
    size_t off = 0;
    int* counts    = (int*)(ws + off);    off += 1024;  // 8 counters, 128B apart
    int* list_tok  = (int*)(ws + off);    off += (size_t)NEXP * N_TOK * 4;
    float* list_w  = (float*)(ws + off);  off += (size_t)NEXP * N_TOK * 4;
    ushort_t* wt1f = (ushort_t*)(ws + off); off += (size_t)NEXP * DIN * HD * 2;
    ushort_t* wt2f = (ushort_t*)(ws + off); off += (size_t)NEXP * HD * HD * 2;
    ushort_t* wotf = (ushort_t*)(ws + off); off += (size_t)HD * DOUT * 2;
    float* y2      = (float*)(ws + off);  off += (size_t)N_TOK * DOUT * 4; // 32MB

    (void)hipMemsetAsync(counts, 0, 1024, stream);
    router_kernel<<<N_TOK / RT_TPB, RT_BLOCK, 0, stream>>>(
        x, Wg, W1, W2, Wo, counts, list_tok, list_w, wt1f, wt2f, wotf);
    expert_kernel<<<NEXP * MAX_TILES, 256, 0, stream>>>(x, counts, list_tok, list_w,
                                                        wt1f, wt2f, wotf, b1, b2, bo, y2, out);
    combine_kernel<<<2048, 256, 0, stream>>>(y2, out);
}

// Round 13
// 175.411 us; speedup vs baseline: 1.0254x; 1.0254x over previous
//
#include <hip/hip_runtime.h>
#include <math.h>

typedef unsigned short ushort_t;
typedef __attribute__((ext_vector_type(8))) short bf16x8;
typedef __attribute__((ext_vector_type(4))) float f32x4;
typedef __attribute__((ext_vector_type(8))) unsigned short u16x8;
typedef __attribute__((ext_vector_type(2))) unsigned int u32x2;
typedef __attribute__((ext_vector_type(4))) unsigned int u32x4;

#define N_TOK 65536
#define DIN 128
#define HD 256
#define DOUT 128
#define NEXP 8
#define MT 64
#define MAX_TILES (N_TOK / MT) /* 1024 */

__device__ __forceinline__ unsigned short f2bf(float f) {
    union { float f; unsigned int i; } v; v.f = f;
    unsigned int i = v.i;
    return (unsigned short)((i + 0x7FFFu + ((i >> 16) & 1u)) >> 16); // RNE
}

#define RT_BLOCK 1024
#define RT_TPB 256    /* tokens per block: 2 passes x 128 */
#define RT_PASS 128

// ---------------------------------------------------------------------------
// Router + weight-pack (R11 verbatim).
// list_w top-1 entries stored NEGATED (sign = carrier flag: expert stores
// w*y+bo to out for top-1, w*y to y2 for top-2).
// ---------------------------------------------------------------------------
__global__ __launch_bounds__(RT_BLOCK)
void router_kernel(const float* __restrict__ x,
                   const float* __restrict__ Wg,
                   const float* __restrict__ W1,
                   const float* __restrict__ W2,
                   const float* __restrict__ Wo,
                   int* __restrict__ counts,
                   int* __restrict__ list_tok,
                   float* __restrict__ list_w,
                   ushort_t* __restrict__ wt1f,
                   ushort_t* __restrict__ wt2f,
                   ushort_t* __restrict__ wotf) {
    __shared__ float xs[RT_PASS * 132];   // 67.6KB, padded rows
    __shared__ float wgsT[NEXP * 132];    // transposed Wg, padded
    __shared__ int lcnt[NEXP];
    __shared__ int lbase[NEXP];
    int tid = threadIdx.x;
    if (tid < NEXP) lcnt[tid] = 0;
    if (tid < DIN * NEXP) {
        int ee = tid & 7, k = tid >> 3;   // Wg[k][e]
        wgsT[ee * 132 + k] = Wg[tid];
    }
    // pack_weights: 256 blocks x 400 chunks = 102400
    if (tid < 400) {
        int id = blockIdx.x * 400 + tid;
        const float* src; ushort_t* dst; int Nn, ksteps, c;
        if (id < 32768) {            // W1
            int ee = id >> 12; c = id & 4095;
            Nn = HD; ksteps = 4; src = W1 + (size_t)ee * DIN * HD; dst = wt1f + (size_t)id * 8;
        } else if (id < 98304) {     // W2
            int t = id - 32768; int ee = t >> 13; c = t & 8191;
            Nn = HD; ksteps = 8; src = W2 + (size_t)ee * HD * HD; dst = wt2f + (size_t)t * 8;
        } else {                     // Wo
            int t = id - 98304; c = t;
            Nn = DOUT; ksteps = 8; src = Wo; dst = wotf + (size_t)t * 8;
        }
        int L = c & 63; int kc = c >> 6;
        int kstep = kc % ksteps; int ntile = kc / ksteps;
        int qq = L >> 4, mm = L & 15;
        int n = ntile * 16 + mm; int k0 = kstep * 32 + qq * 8;
        u16x8 v;
#pragma unroll
        for (int j = 0; j < 8; j++) v[j] = f2bf(src[(size_t)(k0 + j) * Nn + n]);
        *(u16x8*)dst = v;
    }

    int e = tid & 7;
    int tl = tid >> 3;          // local token row, 0..127
    int re0[2], re1[2], rp0[2], rp1[2];
    float rw0[2], rw1[2];

#pragma unroll
    for (int p = 0; p < 2; p++) {
        __syncthreads();  // p0: wgsT/lcnt ready; p1: all lanes done reading xs
        // stage 128 token rows coalescedly
        {
            int row = tid >> 3;
            int f4 = tid & 7;
            const float4* src = (const float4*)(x + (size_t)(blockIdx.x * RT_TPB + p * RT_PASS + row) * DIN);
            float4* drow = (float4*)(xs + row * 132);
#pragma unroll
            for (int j = 0; j < 4; j++)
                drow[f4 + 8 * j] = src[f4 + 8 * j];
        }
        __syncthreads();

        const float4* xr = (const float4*)(xs + tl * 132);
        const float4* wv4 = (const float4*)(wgsT + e * 132);
        float lg = 0.f;
#pragma unroll 8
        for (int kk = 0; kk < 32; kk++) {
            float4 xv = xr[kk];
            float4 wv = wv4[kk];
            lg += xv.x * wv.x;
            lg += xv.y * wv.y;
            lg += xv.z * wv.z;
            lg += xv.w * wv.w;
        }
        // top-1 over the 8 lanes of this token (ties -> lowest expert index)
        float v0 = lg; int e0 = e;
#pragma unroll
        for (int d = 1; d < 8; d <<= 1) {
            float ov = __shfl_xor(v0, d, 64);
            int oe = __shfl_xor(e0, d, 64);
            if (ov > v0 || (ov == v0 && oe < e0)) { v0 = ov; e0 = oe; }
        }
        // top-2: mask out e0, reduce again
        float mv = (e == e0) ? -3.0e38f : lg;
        float v1 = mv; int e1 = e;
#pragma unroll
        for (int d = 1; d < 8; d <<= 1) {
            float ov = __shfl_xor(v1, d, 64);
            int oe = __shfl_xor(e1, d, 64);
            if (ov > v1 || (ov == v1 && oe < e1)) { v1 = ov; e1 = oe; }
        }
        float t = expf(v1 - v0);
        float inv = 1.0f / (1.0f + t);
        re0[p] = e0; re1[p] = e1;
        rw0[p] = inv; rw1[p] = t * inv;
        if (e == 0) {       // writer lane: local ranks unique across passes
            rp0[p] = atomicAdd(&lcnt[e0], 1);
            rp1[p] = atomicAdd(&lcnt[e1], 1);
        }
    }
    __syncthreads();
    if (tid < NEXP) lbase[tid] = atomicAdd(&counts[tid * 32], lcnt[tid]);
    __syncthreads();
    if (e == 0) {
#pragma unroll
        for (int p = 0; p < 2; p++) {
            int n = blockIdx.x * RT_TPB + p * RT_PASS + tl;
            int q0 = lbase[re0[p]] + rp0[p];
            list_tok[re0[p] * N_TOK + q0] = n;
            list_w[re0[p] * N_TOK + q0] = -rw0[p];   // negative = top-1 (out, +bo)
            int q1 = lbase[re1[p]] + rp1[p];
            list_tok[re1[p] * N_TOK + q1] = n;
            list_w[re1[p] * N_TOK + q1] = rw1[p];    // positive = top-2 (y2)
        }
    }
}

// ---------------------------------------------------------------------------
// Fused per-expert MLP, SWAPPED-GEMM form.
// ROUND-13: 512-thread blocks (8 waves), HALF tile per wave.
//   R12 failed to raise occupancy because 64-AGPR acc + ~80 VGPR can't fit
//   128 regs. Fix the decomposition instead: each wave owns 32 h-rows
//   (acc[2][4] = 32 AGPR) in GEMM1/2 and a 32x32 output quadrant in GEMM3
//   (acc3[2][2] = 16). Per-wave live set ~95-100 regs -> 5-6 waves/SIMD
//   (LDS caps 3 blocks/CU x 8 waves = 24 waves/CU) vs 12 before: the TLP
//   this latency-bound kernel (MfmaUtil 20/VALU 24/Occ 27, all low) needs.
//   Index remap (algebra vs R6-verified chunk math): ntile = w*2+rtl ->
//   ks2 = w, q2 = (rtl*2+(q>>1))&3; GEMM3: tt = (w>>2)*2+mt, col-tile =
//   (w&3)*2+nt (each of the 32 16x16 output tiles exactly once).
//   SPILL WATCH: WRITE_SIZE must stay 65.5MB; any jump = spill = revert.
// NO ATOMICS: top-1 entries plain-store w*y+bo into out; top-2 entries
// store w*y into y2; trailing combine kernel does out += y2.
// ---------------------------------------------------------------------------
__global__ __launch_bounds__(512, 4)
void expert_kernel(const float* __restrict__ x,
                   const int* __restrict__ counts,
                   const int* __restrict__ list_tok,
                   const float* __restrict__ list_w,
                   const ushort_t* __restrict__ wt1f,
                   const ushort_t* __restrict__ wt2f,
                   const ushort_t* __restrict__ wotf,
                   const float* __restrict__ b1,
                   const float* __restrict__ b2,
                   const float* __restrict__ bo,
                   float* __restrict__ y2,
                   float* __restrict__ out) {
    int e = blockIdx.x & 7;
    int tile = blockIdx.x >> 3;
    int cnt = counts[e * 32];
    int base = tile * MT;
    if (base >= cnt) return;
    int rows = cnt - base; if (rows > MT) rows = MT;

    __shared__ __align__(16) ushort_t bufA[8192];  // 16KB: x chunks
    __shared__ __align__(16) ushort_t bufH[16384]; // 32KB: h1, then h2
    __shared__ int toks_s[MT];
    __shared__ float wts_s[MT];

    int tid = threadIdx.x;
    int lane = tid & 63;
    int w = tid >> 6;          // wave 0..7
    int q = lane >> 4;
    int mcol = lane & 15;

    const bf16x8* W1A = (const bf16x8*)(wt1f + (size_t)e * 4096 * 8);
    const bf16x8* W2A = (const bf16x8*)(wt2f + (size_t)e * 8192 * 8);
    const bf16x8* WoB = (const bf16x8*)wotf;
    const bf16x8* Albs = (const bf16x8*)bufA;
    const bf16x8* Hlbs = (const bf16x8*)bufH;

    if (tid < MT) {
        int rr = tid < rows ? tid : rows - 1;
        toks_s[tid] = list_tok[(size_t)e * N_TOK + base + rr];
        wts_s[tid] = list_w[(size_t)e * N_TOK + base + rr];
    }

    // stage x tile (fp32 -> bf16) into bufA, kchunk-fast (coalesced 512B/row)
    for (int c = tid; c < 1024; c += 512) {
        int row = c >> 4;
        int kchunk = c & 15;
        int rr = row < rows ? row : rows - 1;
        int tok = list_tok[(size_t)e * N_TOK + base + rr];
        const float4* src = (const float4*)(x + (size_t)tok * DIN + kchunk * 8);
        float4 lo = src[0], hi = src[1];
        unsigned p0, p1, p2, p3;
        asm("v_cvt_pk_bf16_f32 %0, %1, %2" : "=v"(p0) : "v"(lo.x), "v"(lo.y));
        asm("v_cvt_pk_bf16_f32 %0, %1, %2" : "=v"(p1) : "v"(lo.z), "v"(lo.w));
        asm("v_cvt_pk_bf16_f32 %0, %1, %2" : "=v"(p2) : "v"(hi.x), "v"(hi.y));
        asm("v_cvt_pk_bf16_f32 %0, %1, %2" : "=v"(p3) : "v"(hi.z), "v"(hi.w));
        int dchunk = ((kchunk >> 2) * 4 + (row >> 4)) * 64 + (kchunk & 3) * 16 + (row & 15);
        u32x4 v; v.x = p0; v.y = p1; v.z = p2; v.w = p3;
        *(u32x4*)(&bufA[dchunk * 8]) = v;
    }
    __syncthreads();

    // ---- GEMM1 (swapped): h1^T[n=256][t=64], wave w owns n rows w*32..+31
    f32x4 acc[2][4]; // [rtl][ct], ntile = w*2 + rtl
#pragma unroll
    for (int rtl = 0; rtl < 2; rtl++)
#pragma unroll
        for (int ct = 0; ct < 4; ct++) acc[rtl][ct] = (f32x4){0.f, 0.f, 0.f, 0.f};
#pragma unroll
    for (int ks = 0; ks < 4; ks++) {
        bf16x8 ar[2];
#pragma unroll
        for (int rtl = 0; rtl < 2; rtl++)
            ar[rtl] = W1A[((w * 2 + rtl) * 4 + ks) * 64 + lane];
        bf16x8 bf_[4];
#pragma unroll
        for (int ct = 0; ct < 4; ct++) bf_[ct] = Albs[(ks * 4 + ct) * 64 + lane];
        __builtin_amdgcn_s_setprio(1);
#pragma unroll
        for (int rtl = 0; rtl < 2; rtl++)
#pragma unroll
            for (int ct = 0; ct < 4; ct++)
                acc[rtl][ct] = __builtin_amdgcn_mfma_f32_16x16x32_bf16(ar[rtl], bf_[ct], acc[rtl][ct], 0, 0, 0);
        __builtin_amdgcn_s_setprio(0);
    }

    // JIT bias load: n0 = w*32 + rtl*16 + q*4
    float4 b1v[2];
#pragma unroll
    for (int rtl = 0; rtl < 2; rtl++)
        b1v[rtl] = *(const float4*)(b1 + e * HD + w * 32 + rtl * 16 + q * 4);

    // epilogue 1: bias + relu -> h1 chunks in bufH (disjoint from bufA).
    // ks2 = w, q2 = (rtl*2 + (q>>1)) & 3 (derived from R6-verified mapping).
#pragma unroll
    for (int rtl = 0; rtl < 2; rtl++) {
        int q2 = (rtl * 2 + (q >> 1)) & 3;
        int uoff = (w * 256 + q2 * 16 + mcol) * 8 + (q & 1) * 4;
#pragma unroll
        for (int ct = 0; ct < 4; ct++) {
            float v0 = acc[rtl][ct][0] + b1v[rtl].x; v0 = v0 > 0.f ? v0 : 0.f;
            float v1 = acc[rtl][ct][1] + b1v[rtl].y; v1 = v1 > 0.f ? v1 : 0.f;
            float v2 = acc[rtl][ct][2] + b1v[rtl].z; v2 = v2 > 0.f ? v2 : 0.f;
            float v3 = acc[rtl][ct][3] + b1v[rtl].w; v3 = v3 > 0.f ? v3 : 0.f;
            unsigned d0, d1;
            asm("v_cvt_pk_bf16_f32 %0, %1, %2" : "=v"(d0) : "v"(v0), "v"(v1));
            asm("v_cvt_pk_bf16_f32 %0, %1, %2" : "=v"(d1) : "v"(v2), "v"(v3));
            u32x2 dd; dd.x = d0; dd.y = d1;
            *(u32x2*)(&bufH[uoff + ct * 512]) = dd;
        }
    }
    __syncthreads(); // h1 complete before GEMM2 reads

    // ---- GEMM2 (swapped): h2^T = W2^T @ h1^T, K=256 ----
    f32x4 acc2[2][4];
#pragma unroll
    for (int rtl = 0; rtl < 2; rtl++)
#pragma unroll
        for (int ct = 0; ct < 4; ct++) acc2[rtl][ct] = (f32x4){0.f, 0.f, 0.f, 0.f};
#pragma unroll
    for (int ks = 0; ks < 8; ks++) {
        bf16x8 ar[2];
#pragma unroll
        for (int rtl = 0; rtl < 2; rtl++)
            ar[rtl] = W2A[((w * 2 + rtl) * 8 + ks) * 64 + lane];
        bf16x8 bf_[4];
#pragma unroll
        for (int ct = 0; ct < 4; ct++) bf_[ct] = Hlbs[(ks * 4 + ct) * 64 + lane];
        __builtin_amdgcn_s_setprio(1);
#pragma unroll
        for (int rtl = 0; rtl < 2; rtl++)
#pragma unroll
            for (int ct = 0; ct < 4; ct++)
                acc2[rtl][ct] = __builtin_amdgcn_mfma_f32_16x16x32_bf16(ar[rtl], bf_[ct], acc2[rtl][ct], 0, 0, 0);
        __builtin_amdgcn_s_setprio(0);
    }

    // JIT bias load
    float4 b2v[2];
#pragma unroll
    for (int rtl = 0; rtl < 2; rtl++)
        b2v[rtl] = *(const float4*)(b2 + e * HD + w * 32 + rtl * 16 + q * 4);

    __syncthreads(); // all waves done reading h1 before h2 overwrite

    // epilogue 2: bias + relu -> h2 chunks
#pragma unroll
    for (int rtl = 0; rtl < 2; rtl++) {
        int q2 = (rtl * 2 + (q >> 1)) & 3;
        int uoff = (w * 256 + q2 * 16 + mcol) * 8 + (q & 1) * 4;
#pragma unroll
        for (int ct = 0; ct < 4; ct++) {
            float v0 = acc2[rtl][ct][0] + b2v[rtl].x; v0 = v0 > 0.f ? v0 : 0.f;
            float v1 = acc2[rtl][ct][1] + b2v[rtl].y; v1 = v1 > 0.f ? v1 : 0.f;
            float v2 = acc2[rtl][ct][2] + b2v[rtl].z; v2 = v2 > 0.f ? v2 : 0.f;
            float v3 = acc2[rtl][ct][3] + b2v[rtl].w; v3 = v3 > 0.f ? v3 : 0.f;
            unsigned d0, d1;
            asm("v_cvt_pk_bf16_f32 %0, %1, %2" : "=v"(d0) : "v"(v0), "v"(v1));
            asm("v_cvt_pk_bf16_f32 %0, %1, %2" : "=v"(d1) : "v"(v2), "v"(v3));
            u32x2 dd; dd.x = d0; dd.y = d1;
            *(u32x2*)(&bufH[uoff + ct * 512]) = dd;
        }
    }
    __syncthreads();

    // ---- GEMM3 (unswapped): y = h2 @ Wo; wave w owns token-half (w>>2)
    //      and col-tiles (w&3)*2 + nt. acc3[2][2] = 16 AGPR.
    f32x4 acc3[2][2]; // [mt][nt]
#pragma unroll
    for (int mt = 0; mt < 2; mt++)
#pragma unroll
        for (int nt = 0; nt < 2; nt++) acc3[mt][nt] = (f32x4){0.f, 0.f, 0.f, 0.f};
#pragma unroll
    for (int ks = 0; ks < 8; ks++) {
        bf16x8 br[2];
#pragma unroll
        for (int nt = 0; nt < 2; nt++)
            br[nt] = WoB[(((w & 3) * 2 + nt) * 8 + ks) * 64 + lane];
        bf16x8 af_[2];
#pragma unroll
        for (int mt = 0; mt < 2; mt++)
            af_[mt] = Hlbs[(ks * 4 + (w >> 2) * 2 + mt) * 64 + lane];
        __builtin_amdgcn_s_setprio(1);
#pragma unroll
        for (int nt = 0; nt < 2; nt++)
#pragma unroll
            for (int mt = 0; mt < 2; mt++)
                acc3[mt][nt] = __builtin_amdgcn_mfma_f32_16x16x32_bf16(af_[mt], br[nt], acc3[mt][nt], 0, 0, 0);
        __builtin_amdgcn_s_setprio(0);
    }
#pragma unroll
    for (int mt = 0; mt < 2; mt++) {
#pragma unroll
        for (int r = 0; r < 4; r++) {
            int row = (w >> 2) * 32 + mt * 16 + q * 4 + r;
            if (row < rows) {
                int tok = toks_s[row];
                float wraw = wts_s[row];
                float wgt = fabsf(wraw);
                bool carrier = wraw < 0.f;   // top-1: store to out, add bo once
                float* dst = (carrier ? out : y2) + (size_t)tok * DOUT;
#pragma unroll
                for (int nt = 0; nt < 2; nt++) {
                    int col = ((w & 3) * 2 + nt) * 16 + mcol;
                    dst[col] = wgt * acc3[mt][nt][r] + (carrier ? bo[col] : 0.f);
                }
            }
        }
    }
}

// ---------------------------------------------------------------------------
// out += y2 (streaming, 96MB total traffic). Every token has exactly one
// top-1 store (already in out) and one top-2 store (in y2).
// ---------------------------------------------------------------------------
__global__ __launch_bounds__(256)
void combine_kernel(const float* __restrict__ y2, float* __restrict__ out) {
    int gid = blockIdx.x * 256 + threadIdx.x;
#pragma unroll
    for (int i = 0; i < 4; i++) {
        int idx = gid + i * (2048 * 256);
        float4 a = ((float4*)out)[idx];
        float4 b = ((const float4*)y2)[idx];
        a.x += b.x; a.y += b.y; a.z += b.z; a.w += b.w;
        ((float4*)out)[idx] = a;
    }
}

extern "C" void kernel_launch(void* const* d_in, const int* in_sizes, int n_in,
                              void* d_out, int out_size, void* d_ws, size_t ws_size,
                              hipStream_t stream) {
    const float* x  = (const float*)d_in[0];
    const float* Wg = (const float*)d_in[1];
    const float* W1 = (const float*)d_in[2];
    const float* b1 = (const float*)d_in[3];
    const float* W2 = (const float*)d_in[4];
    const float* b2 = (const float*)d_in[5];
    const float* Wo = (const float*)d_in[6];
    const float* bo = (const float*)d_in[7];
    float* out = (float*)d_out;

    char* ws = (char*)d_ws;
    size_t off = 0;
    int* counts    = (int*)(ws + off);    off += 1024;  // 8 counters, 128B apart
    int* list_tok  = (int*)(ws + off);    off += (size_t)NEXP * N_TOK * 4;
    float* list_w  = (float*)(ws + off);  off += (size_t)NEXP * N_TOK * 4;
    ushort_t* wt1f = (ushort_t*)(ws + off); off += (size_t)NEXP * DIN * HD * 2;
    ushort_t* wt2f = (ushort_t*)(ws + off); off += (size_t)NEXP * HD * HD * 2;
    ushort_t* wotf = (ushort_t*)(ws + off); off += (size_t)HD * DOUT * 2;
    float* y2      = (float*)(ws + off);  off += (size_t)N_TOK * DOUT * 4; // 32MB

    (void)hipMemsetAsync(counts, 0, 1024, stream);
    router_kernel<<<N_TOK / RT_TPB, RT_BLOCK, 0, stream>>>(
        x, Wg, W1, W2, Wo, counts, list_tok, list_w, wt1f, wt2f, wotf);
    expert_kernel<<<NEXP * MAX_TILES, 512, 0, stream>>>(x, counts, list_tok, list_w,
                                                        wt1f, wt2f, wotf, b1, b2, bo, y2, out);
    combine_kernel<<<2048, 256, 0, stream>>>(y2, out);
}